// Round 4
// baseline (16813.272 us; speedup 1.0000x reference)
//
#include <hip/hip_runtime.h>
#include <hip/hip_bf16.h>

#define T_SEQ 8192
#define E_DIM 256
#define H_DIM 512
#define G4    2048   // 4*H
#define NBD   128    // blocks per direction
#define JPB   4      // h-elements per block

// ======================================================================
// K1: pre[dir][t][0:2048] = emb[sent(dir,t)] @ W_ih[dir]^T + (b_ih+b_hh)
// ======================================================================
__global__ __launch_bounds__(256, 4)
void k_pre(const int* __restrict__ sent, const float* __restrict__ emb,
           const float* __restrict__ Wf, const float* __restrict__ Wb,
           const float* __restrict__ bif, const float* __restrict__ bhf,
           const float* __restrict__ bib, const float* __restrict__ bhb,
           float* __restrict__ pre)
{
    const int jt  = blockIdx.x;
    const int tt  = blockIdx.y;
    const int dir = blockIdx.z;
    const float* W  = dir ? Wb : Wf;
    const float* bi = dir ? bib : bif;
    const float* bh = dir ? bhb : bhf;
    float* pred = pre + (size_t)dir * T_SEQ * G4;

    __shared__ float xs[64][65];
    __shared__ float ws[64][65];
    __shared__ int   ss[64];

    const int tid = threadIdx.x;
    if (tid < 64) {
        int trow = tt * 64 + tid;
        ss[tid] = sent[dir ? (T_SEQ - 1 - trow) : trow];
    }

    const int ty = tid >> 4, tx = tid & 15;
    const int lrow  = tid >> 2;
    const int cbase = (tid & 3) * 16;

    float acc[4][4] = {{0.f}};

    for (int kk0 = 0; kk0 < E_DIM; kk0 += 64) {
        __syncthreads();
        #pragma unroll
        for (int c = 0; c < 4; ++c) {
            int col = cbase + c * 4;
            float4 xv = *reinterpret_cast<const float4*>(emb + (size_t)ss[lrow] * E_DIM + kk0 + col);
            float4 wv = *reinterpret_cast<const float4*>(W + (size_t)(jt * 64 + lrow) * E_DIM + kk0 + col);
            xs[lrow][col+0] = xv.x; xs[lrow][col+1] = xv.y; xs[lrow][col+2] = xv.z; xs[lrow][col+3] = xv.w;
            ws[lrow][col+0] = wv.x; ws[lrow][col+1] = wv.y; ws[lrow][col+2] = wv.z; ws[lrow][col+3] = wv.w;
        }
        __syncthreads();
        #pragma unroll 8
        for (int k = 0; k < 64; ++k) {
            float a0 = xs[ty*4+0][k], a1 = xs[ty*4+1][k], a2 = xs[ty*4+2][k], a3 = xs[ty*4+3][k];
            float b0 = ws[tx*4+0][k], b1 = ws[tx*4+1][k], b2 = ws[tx*4+2][k], b3 = ws[tx*4+3][k];
            acc[0][0] = fmaf(a0,b0,acc[0][0]); acc[0][1] = fmaf(a0,b1,acc[0][1]);
            acc[0][2] = fmaf(a0,b2,acc[0][2]); acc[0][3] = fmaf(a0,b3,acc[0][3]);
            acc[1][0] = fmaf(a1,b0,acc[1][0]); acc[1][1] = fmaf(a1,b1,acc[1][1]);
            acc[1][2] = fmaf(a1,b2,acc[1][2]); acc[1][3] = fmaf(a1,b3,acc[1][3]);
            acc[2][0] = fmaf(a2,b0,acc[2][0]); acc[2][1] = fmaf(a2,b1,acc[2][1]);
            acc[2][2] = fmaf(a2,b2,acc[2][2]); acc[2][3] = fmaf(a2,b3,acc[2][3]);
            acc[3][0] = fmaf(a3,b0,acc[3][0]); acc[3][1] = fmaf(a3,b1,acc[3][1]);
            acc[3][2] = fmaf(a3,b2,acc[3][2]); acc[3][3] = fmaf(a3,b3,acc[3][3]);
        }
    }

    const int colg = jt * 64 + tx * 4;
    float bs[4];
    #pragma unroll
    for (int j = 0; j < 4; ++j) bs[j] = bi[colg + j] + bh[colg + j];
    #pragma unroll
    for (int i = 0; i < 4; ++i) {
        float4 r;
        r.x = acc[i][0] + bs[0]; r.y = acc[i][1] + bs[1];
        r.z = acc[i][2] + bs[2]; r.w = acc[i][3] + bs[3];
        *reinterpret_cast<float4*>(pred + (size_t)(tt*64 + ty*4 + i) * G4 + colg) = r;
    }
}

// ---------- fast activations (no NaN for large |x|) ----------
__device__ __forceinline__ float sigmoid_f(float x) {
    return 1.f / (1.f + __expf(-x));
}
__device__ __forceinline__ float tanh_f(float x) {
    float e = __expf(2.f * fabsf(x));            // inf ok: 2/(inf+1)=0
    float r = 1.f - 2.f / (e + 1.f);
    return copysignf(r, x);
}

// ---------- 64-lane sum via DPP (VALU pipe, no LDS); result in lane 63 ----
template <int CTRL, int RM>
__device__ __forceinline__ float dpp_add(float x) {
    int m = __builtin_amdgcn_update_dpp(0, __float_as_int(x), CTRL, RM, 0xf, true);
    return x + __int_as_float(m);
}
__device__ __forceinline__ float dpp_reduce64(float x) {
    x = dpp_add<0x111, 0xf>(x);   // row_shr:1
    x = dpp_add<0x112, 0xf>(x);   // row_shr:2
    x = dpp_add<0x114, 0xf>(x);   // row_shr:4
    x = dpp_add<0x118, 0xf>(x);   // row_shr:8  -> lane15 of each row16 = row sum
    x = dpp_add<0x142, 0xa>(x);   // row_bcast15 into rows 1,3
    x = dpp_add<0x143, 0xc>(x);   // row_bcast31 into rows 2,3 -> lane63 total
    return x;
}

// ======================================================================
// K2: two LSTM scans. 256 persistent blocks (128/dir) x 1024 threads.
// One wave per gate-row (16 rows/block, 4 h-elems/block). 8 weights per
// thread (2 pinned float4) -> trivially register-resident. h broadcast
// via 512-word LDS stage; 64-lane row reduce on VALU via DPP.
// h exchange across blocks: step-tagged 64-bit agent-scope atomics,
// parity double-buffered (proven protocol, rounds 1-2).
// ======================================================================
__global__ __launch_bounds__(1024, 4)
void k_scan(const float* __restrict__ pre,
            const float* __restrict__ Whhf, const float* __restrict__ Whhb,
            const float* __restrict__ h0, const float* __restrict__ c0,
            float* __restrict__ hcat, unsigned long long* __restrict__ hbuf)
{
    const int bid  = blockIdx.x;
    const int dir  = bid >> 7;          // 0..1
    const int b    = bid & (NBD - 1);   // 0..127
    const int tid  = threadIdx.x;
    const int wv   = tid >> 6;          // 0..15 (wave = one gate-row)
    const int lane = tid & 63;
    const int g    = wv & 3;            // gate (PyTorch order i,f,g,o)
    const int jj   = wv >> 2;           // 0..3
    const int j_global = b * JPB + jj;  // 0..511
    const int row  = g * H_DIM + j_global;

    // 8 weights/thread: cols {4*lane..+3} and {256+4*lane..+3}
    const float* Whh = dir ? Whhb : Whhf;
    float4 wa = *reinterpret_cast<const float4*>(Whh + (size_t)row * H_DIM + 4 * lane);
    float4 wb = *reinterpret_cast<const float4*>(Whh + (size_t)row * H_DIM + 256 + 4 * lane);
    float w[8] = {wa.x, wa.y, wa.z, wa.w, wb.x, wb.y, wb.z, wb.w};
    #pragma unroll
    for (int k = 0; k < 8; ++k) asm volatile("" : "+v"(w[k]));

    unsigned long long* hb = hbuf + dir * 1024;      // [parity][512]
    const float* pred = pre + (size_t)dir * T_SEQ * G4;

    __shared__ float hsh[2][512];
    __shared__ float gact[16];

    // publish own h0 slots (tag 0, parity 0)
    if (tid < JPB) {
        int j = b * JPB + tid;
        unsigned long long pv = (unsigned long long)__float_as_uint(h0[dir * H_DIM + j]);
        __hip_atomic_store(&hb[j], pv, __ATOMIC_RELAXED, __HIP_MEMORY_SCOPE_AGENT);
    }
    __threadfence();
    __syncthreads();

    float c_reg = (tid < JPB) ? c0[dir * H_DIM + b * JPB + tid] : 0.f;
    float pre_row = (lane == 63) ? pred[row] : 0.f;  // prefetch t=0 (lane63 owns it)

    for (int t = 0; t < T_SEQ; ++t) {
        const int par = t & 1;
        if (tid < 512) {
            unsigned long long v;
            do {
                v = __hip_atomic_load(&hb[par * 512 + tid], __ATOMIC_RELAXED, __HIP_MEMORY_SCOPE_AGENT);
            } while ((unsigned)(v >> 32) != (unsigned)t);
            hsh[par][tid] = __uint_as_float((unsigned)v);
        }
        __syncthreads();

        // matvec: 8 cols per lane, bank-even b128 reads
        const float* hv = hsh[par];
        float4 ha = *reinterpret_cast<const float4*>(hv + 4 * lane);
        float4 hbv = *reinterpret_cast<const float4*>(hv + 256 + 4 * lane);
        float a = 0.f;
        a = fmaf(ha.x,  w[0], a); a = fmaf(ha.y,  w[1], a);
        a = fmaf(ha.z,  w[2], a); a = fmaf(ha.w,  w[3], a);
        a = fmaf(hbv.x, w[4], a); a = fmaf(hbv.y, w[5], a);
        a = fmaf(hbv.z, w[6], a); a = fmaf(hbv.w, w[7], a);
        a = dpp_reduce64(a);                          // lane63 = row sum

        if (lane == 63) {
            float v = a + pre_row;
            gact[wv] = (g == 2) ? tanh_f(v) : sigmoid_f(v);
            if (t + 1 < T_SEQ)                        // prefetch next pre
                pre_row = pred[(size_t)(t + 1) * G4 + row];
        }
        __syncthreads();

        if (tid < JPB) {
            float ai = gact[tid * 4 + 0];
            float af = gact[tid * 4 + 1];
            float ag = gact[tid * 4 + 2];
            float ao = gact[tid * 4 + 3];
            c_reg = af * c_reg + ai * ag;
            float h = ao * tanh_f(c_reg);
            int j = b * JPB + tid;
            unsigned long long pv = ((unsigned long long)(unsigned)(t + 1) << 32)
                                  | (unsigned long long)__float_as_uint(h);
            __hip_atomic_store(&hb[((t + 1) & 1) * 512 + j], pv,
                               __ATOMIC_RELAXED, __HIP_MEMORY_SCOPE_AGENT);
            int ta = dir ? (T_SEQ - 1 - t) : t;
            hcat[(size_t)ta * 1024 + dir * H_DIM + j] = h;
        }
        // gact(t+1) writes happen only after next iteration's barrier,
        // which the tid<JPB readers must also reach -> no WAR hazard.
    }
}

// ======================================================================
// K3: out[t][k] = hcat[t] . W_out[k] + b_out[k]
// ======================================================================
__global__ __launch_bounds__(256, 4)
void k_out(const float* __restrict__ hcat, const float* __restrict__ Wout,
           const float* __restrict__ bout, float* __restrict__ out)
{
    const int lane = threadIdx.x & 63;
    const int gw   = (blockIdx.x * 256 + threadIdx.x) >> 6;
    for (int t = gw; t < T_SEQ; t += 1024) {
        const float* hr = hcat + (size_t)t * 1024 + lane * 16;
        float4 h4[4];
        #pragma unroll
        for (int i = 0; i < 4; ++i) h4[i] = *reinterpret_cast<const float4*>(hr + 4 * i);
        float res = 0.f;
        for (int k = 0; k < 32; ++k) {
            const float* wr = Wout + (size_t)k * 1024 + lane * 16;
            float p = 0.f;
            #pragma unroll
            for (int i = 0; i < 4; ++i) {
                float4 w4 = *reinterpret_cast<const float4*>(wr + 4 * i);
                p = fmaf(h4[i].x, w4.x, p); p = fmaf(h4[i].y, w4.y, p);
                p = fmaf(h4[i].z, w4.z, p); p = fmaf(h4[i].w, w4.w, p);
            }
            p += __shfl_xor(p, 1);  p += __shfl_xor(p, 2);  p += __shfl_xor(p, 4);
            p += __shfl_xor(p, 8);  p += __shfl_xor(p, 16); p += __shfl_xor(p, 32);
            if (lane == k) res = p;
        }
        if (lane < 32) out[(size_t)t * 32 + lane] = res + bout[lane];
    }
}

// ======================================================================
extern "C" void kernel_launch(void* const* d_in, const int* in_sizes, int n_in,
                              void* d_out, int out_size, void* d_ws, size_t ws_size,
                              hipStream_t stream) {
    const int*   sent = (const int*)  d_in[0];
    const float* emb  = (const float*)d_in[1];
    const float* Wihf = (const float*)d_in[2];
    const float* Whhf = (const float*)d_in[3];
    const float* bihf = (const float*)d_in[4];
    const float* bhhf = (const float*)d_in[5];
    const float* Wihb = (const float*)d_in[6];
    const float* Whhb = (const float*)d_in[7];
    const float* bihb = (const float*)d_in[8];
    const float* bhhb = (const float*)d_in[9];
    const float* Wout = (const float*)d_in[10];
    const float* bout = (const float*)d_in[11];
    const float* h0   = (const float*)d_in[12];
    const float* c0   = (const float*)d_in[13];
    float* out = (float*)d_out;

    // workspace layout: pre (128 MB) | hcat (32 MB) | hbuf (16 KB)
    float* pre  = (float*)d_ws;
    float* hcat = pre + (size_t)2 * T_SEQ * G4;
    unsigned long long* hbuf = (unsigned long long*)(hcat + (size_t)T_SEQ * 1024);

    dim3 g1(G4 / 64, T_SEQ / 64, 2);
    k_pre<<<g1, 256, 0, stream>>>(sent, emb, Wihf, Wihb, bihf, bhhf, bihb, bhhb, pre);
    k_scan<<<2 * NBD, 1024, 0, stream>>>(pre, Whhf, Whhb, h0, c0, hcat, hbuf);
    k_out<<<256, 256, 0, stream>>>(hcat, Wout, bout, out);
}

// Round 5
// 12393.351 us; speedup vs baseline: 1.3566x; 1.3566x over previous
//
#include <hip/hip_runtime.h>
#include <hip/hip_bf16.h>

#define T_SEQ 8192
#define E_DIM 256
#define H_DIM 512
#define G4    2048   // 4*H
#define NBD   32     // blocks per direction
#define JPB   16     // h-elements per block

// ======================================================================
// K1: pre[dir][t][0:2048] = emb[sent(dir,t)] @ W_ih[dir]^T + (b_ih+b_hh)
// ======================================================================
__global__ __launch_bounds__(256, 4)
void k_pre(const int* __restrict__ sent, const float* __restrict__ emb,
           const float* __restrict__ Wf, const float* __restrict__ Wb,
           const float* __restrict__ bif, const float* __restrict__ bhf,
           const float* __restrict__ bib, const float* __restrict__ bhb,
           float* __restrict__ pre)
{
    const int jt  = blockIdx.x;
    const int tt  = blockIdx.y;
    const int dir = blockIdx.z;
    const float* W  = dir ? Wb : Wf;
    const float* bi = dir ? bib : bif;
    const float* bh = dir ? bhb : bhf;
    float* pred = pre + (size_t)dir * T_SEQ * G4;

    __shared__ float xs[64][65];
    __shared__ float ws[64][65];
    __shared__ int   ss[64];

    const int tid = threadIdx.x;
    if (tid < 64) {
        int trow = tt * 64 + tid;
        ss[tid] = sent[dir ? (T_SEQ - 1 - trow) : trow];
    }

    const int ty = tid >> 4, tx = tid & 15;
    const int lrow  = tid >> 2;
    const int cbase = (tid & 3) * 16;

    float acc[4][4] = {{0.f}};

    for (int kk0 = 0; kk0 < E_DIM; kk0 += 64) {
        __syncthreads();
        #pragma unroll
        for (int c = 0; c < 4; ++c) {
            int col = cbase + c * 4;
            float4 xv = *reinterpret_cast<const float4*>(emb + (size_t)ss[lrow] * E_DIM + kk0 + col);
            float4 wv = *reinterpret_cast<const float4*>(W + (size_t)(jt * 64 + lrow) * E_DIM + kk0 + col);
            xs[lrow][col+0] = xv.x; xs[lrow][col+1] = xv.y; xs[lrow][col+2] = xv.z; xs[lrow][col+3] = xv.w;
            ws[lrow][col+0] = wv.x; ws[lrow][col+1] = wv.y; ws[lrow][col+2] = wv.z; ws[lrow][col+3] = wv.w;
        }
        __syncthreads();
        #pragma unroll 8
        for (int k = 0; k < 64; ++k) {
            float a0 = xs[ty*4+0][k], a1 = xs[ty*4+1][k], a2 = xs[ty*4+2][k], a3 = xs[ty*4+3][k];
            float b0 = ws[tx*4+0][k], b1 = ws[tx*4+1][k], b2 = ws[tx*4+2][k], b3 = ws[tx*4+3][k];
            acc[0][0] = fmaf(a0,b0,acc[0][0]); acc[0][1] = fmaf(a0,b1,acc[0][1]);
            acc[0][2] = fmaf(a0,b2,acc[0][2]); acc[0][3] = fmaf(a0,b3,acc[0][3]);
            acc[1][0] = fmaf(a1,b0,acc[1][0]); acc[1][1] = fmaf(a1,b1,acc[1][1]);
            acc[1][2] = fmaf(a1,b2,acc[1][2]); acc[1][3] = fmaf(a1,b3,acc[1][3]);
            acc[2][0] = fmaf(a2,b0,acc[2][0]); acc[2][1] = fmaf(a2,b1,acc[2][1]);
            acc[2][2] = fmaf(a2,b2,acc[2][2]); acc[2][3] = fmaf(a2,b3,acc[2][3]);
            acc[3][0] = fmaf(a3,b0,acc[3][0]); acc[3][1] = fmaf(a3,b1,acc[3][1]);
            acc[3][2] = fmaf(a3,b2,acc[3][2]); acc[3][3] = fmaf(a3,b3,acc[3][3]);
        }
    }

    const int colg = jt * 64 + tx * 4;
    float bs[4];
    #pragma unroll
    for (int j = 0; j < 4; ++j) bs[j] = bi[colg + j] + bh[colg + j];
    #pragma unroll
    for (int i = 0; i < 4; ++i) {
        float4 r;
        r.x = acc[i][0] + bs[0]; r.y = acc[i][1] + bs[1];
        r.z = acc[i][2] + bs[2]; r.w = acc[i][3] + bs[3];
        *reinterpret_cast<float4*>(pred + (size_t)(tt*64 + ty*4 + i) * G4 + colg) = r;
    }
}

// ---------- fast activations (no NaN for large |x|) ----------
__device__ __forceinline__ float sigmoid_f(float x) {
    return 1.f / (1.f + __expf(-x));
}
__device__ __forceinline__ float tanh_f(float x) {
    float e = __expf(2.f * fabsf(x));            // inf ok: 2/(inf+1)=0
    float r = 1.f - 2.f / (e + 1.f);
    return copysignf(r, x);
}

// ======================================================================
// K2: two LSTM scans. 64 persistent blocks (32/dir) x 512 threads.
// Block owns 16 h-outputs (64 gate-rows). Thread: 8 rows x 8 cols = 64
// register-resident weights (launch_bounds(512,2) -> 256-VGPR cap, no
// spill pressure -- R1/R2's spill was the 128-cap). Per step: 2
// conflict-free ds_read_b128 h-loads, 64 FMAs, multi-value xor butterfly
// (lane L ends with row (L&7) total), per-lane activation, shfl gate
// collect, lanes 0/4 per wave update c and publish.
// dir = bit2 of blockIdx: each direction's h-traffic stays on half the
// XCDs under round-robin dispatch (perf heuristic only).
// ======================================================================
__global__ __launch_bounds__(512, 2)
void k_scan(const float* __restrict__ pre,
            const float* __restrict__ Whhf, const float* __restrict__ Whhb,
            const float* __restrict__ h0, const float* __restrict__ c0,
            float* __restrict__ hcat, unsigned long long* __restrict__ hbuf)
{
    const int bid  = blockIdx.x;
    const int dir  = (bid >> 2) & 1;
    const int b    = (bid >> 3) * 4 + (bid & 3);   // 0..31 within dir
    const int tid  = threadIdx.x;
    const int wv   = tid >> 6;          // 0..7
    const int lane = tid & 63;
    const int r    = lane & 7;          // this lane's home row (post-reduce)
    const int gme  = r & 3;             // gate of home row
    const int j_me = b * JPB + wv * 2 + (r >> 2);
    const int row_me = gme * H_DIM + j_me;          // for pre prefetch

    // 64 weights: 8 rows (wave's rows) x 8 cols (4*lane.. / 256+4*lane..)
    const float* Whh = dir ? Whhb : Whhf;
    float w[8][8];
    #pragma unroll
    for (int r2 = 0; r2 < 8; ++r2) {
        int rr = (r2 & 3) * H_DIM + b * JPB + wv * 2 + (r2 >> 2);
        float4 wa = *reinterpret_cast<const float4*>(Whh + (size_t)rr * H_DIM + 4 * lane);
        float4 wb = *reinterpret_cast<const float4*>(Whh + (size_t)rr * H_DIM + 256 + 4 * lane);
        w[r2][0]=wa.x; w[r2][1]=wa.y; w[r2][2]=wa.z; w[r2][3]=wa.w;
        w[r2][4]=wb.x; w[r2][5]=wb.y; w[r2][6]=wb.z; w[r2][7]=wb.w;
    }
    #pragma unroll
    for (int r2 = 0; r2 < 8; ++r2)
        #pragma unroll
        for (int c = 0; c < 8; ++c) asm volatile("" : "+v"(w[r2][c]));

    unsigned long long* hb = hbuf + dir * 1024;      // [parity][512]
    const float* pred = pre + (size_t)dir * T_SEQ * G4;

    __shared__ float hsh[2][512];

    // publish own h0 slots (tag 0, parity 0)
    if (tid < JPB) {
        int j = b * JPB + tid;
        unsigned long long pv = (unsigned long long)__float_as_uint(h0[dir * H_DIM + j]);
        __hip_atomic_store(&hb[j], pv, __ATOMIC_RELAXED, __HIP_MEMORY_SCOPE_AGENT);
    }
    __syncthreads();

    const bool owner = (lane == 0) || (lane == 4);   // j = b*16+wv*2+(lane>>2)
    float c_reg = owner ? c0[dir * H_DIM + j_me] : 0.f;
    float pre_row = pred[row_me];                    // t=0 (8 lanes share addr -> bcast)

    for (int t = 0; t < T_SEQ; ++t) {
        const int par = t & 1;
        {
            unsigned long long v;
            do {
                v = __hip_atomic_load(&hb[par * 512 + tid], __ATOMIC_RELAXED, __HIP_MEMORY_SCOPE_AGENT);
            } while ((unsigned)(v >> 32) != (unsigned)t);
            hsh[par][tid] = __uint_as_float((unsigned)v);
        }
        __syncthreads();

        // matvec: 8 rows x 8 cols; h loads conflict-free b128
        const float* hv = hsh[par];
        float4 ha  = *reinterpret_cast<const float4*>(hv + 4 * lane);
        float4 hb4 = *reinterpret_cast<const float4*>(hv + 256 + 4 * lane);
        float acc[8];
        #pragma unroll
        for (int r2 = 0; r2 < 8; ++r2) {
            float a = 0.f;
            a = fmaf(ha.x,  w[r2][0], a); a = fmaf(ha.y,  w[r2][1], a);
            a = fmaf(ha.z,  w[r2][2], a); a = fmaf(ha.w,  w[r2][3], a);
            a = fmaf(hb4.x, w[r2][4], a); a = fmaf(hb4.y, w[r2][5], a);
            a = fmaf(hb4.z, w[r2][6], a); a = fmaf(hb4.w, w[r2][7], a);
            acc[r2] = a;
        }

        // multi-value butterfly: 8 -> 4 -> 2 -> 1 (rows keyed by lane bits),
        // then full reduce over oct-groups. Lane L ends with row (L&7) total.
        float v4[4];
        #pragma unroll
        for (int k = 0; k < 4; ++k) {
            float keep = (lane & 1) ? acc[2*k+1] : acc[2*k];
            float send = (lane & 1) ? acc[2*k]   : acc[2*k+1];
            v4[k] = keep + __shfl_xor(send, 1);
        }
        float v2[2];
        #pragma unroll
        for (int k = 0; k < 2; ++k) {
            float keep = (lane & 2) ? v4[2*k+1] : v4[2*k];
            float send = (lane & 2) ? v4[2*k]   : v4[2*k+1];
            v2[k] = keep + __shfl_xor(send, 2);
        }
        float keep = (lane & 4) ? v2[1] : v2[0];
        float send = (lane & 4) ? v2[0] : v2[1];
        float vr = keep + __shfl_xor(send, 4);
        vr += __shfl_xor(vr, 8);
        vr += __shfl_xor(vr, 16);
        vr += __shfl_xor(vr, 32);

        float gv = vr + pre_row;                     // my home row's gate value

        if (t + 1 < T_SEQ)                           // prefetch next pre
            pre_row = pred[(size_t)(t + 1) * G4 + row_me];

        float act = (gme == 2) ? tanh_f(gv) : sigmoid_f(gv);

        // collect f,g,o onto gate-i lanes (r&3==0)
        float af = __shfl_xor(act, 1);
        float ag = __shfl_xor(act, 2);
        float ao = __shfl_xor(act, 3);

        if (owner) {                                 // lanes 0 and 4: r=0,4 (gate i)
            c_reg = af * c_reg + act * ag;
            float h = ao * tanh_f(c_reg);
            unsigned long long pv = ((unsigned long long)(unsigned)(t + 1) << 32)
                                  | (unsigned long long)__float_as_uint(h);
            __hip_atomic_store(&hb[((t + 1) & 1) * 512 + j_me], pv,
                               __ATOMIC_RELAXED, __HIP_MEMORY_SCOPE_AGENT);
            int ta = dir ? (T_SEQ - 1 - t) : t;
            hcat[(size_t)ta * 1024 + dir * H_DIM + j_me] = h;
        }
        // hsh parity double-buffered; next iteration's barrier orders
        // reads-before-overwrite (single barrier per step suffices).
    }
}

// ======================================================================
// K3: out[t][k] = hcat[t] . W_out[k] + b_out[k]
// ======================================================================
__global__ __launch_bounds__(256, 4)
void k_out(const float* __restrict__ hcat, const float* __restrict__ Wout,
           const float* __restrict__ bout, float* __restrict__ out)
{
    const int lane = threadIdx.x & 63;
    const int gw   = (blockIdx.x * 256 + threadIdx.x) >> 6;
    for (int t = gw; t < T_SEQ; t += 1024) {
        const float* hr = hcat + (size_t)t * 1024 + lane * 16;
        float4 h4[4];
        #pragma unroll
        for (int i = 0; i < 4; ++i) h4[i] = *reinterpret_cast<const float4*>(hr + 4 * i);
        float res = 0.f;
        for (int k = 0; k < 32; ++k) {
            const float* wr = Wout + (size_t)k * 1024 + lane * 16;
            float p = 0.f;
            #pragma unroll
            for (int i = 0; i < 4; ++i) {
                float4 w4 = *reinterpret_cast<const float4*>(wr + 4 * i);
                p = fmaf(h4[i].x, w4.x, p); p = fmaf(h4[i].y, w4.y, p);
                p = fmaf(h4[i].z, w4.z, p); p = fmaf(h4[i].w, w4.w, p);
            }
            p += __shfl_xor(p, 1);  p += __shfl_xor(p, 2);  p += __shfl_xor(p, 4);
            p += __shfl_xor(p, 8);  p += __shfl_xor(p, 16); p += __shfl_xor(p, 32);
            if (lane == k) res = p;
        }
        if (lane < 32) out[(size_t)t * 32 + lane] = res + bout[lane];
    }
}

// ======================================================================
extern "C" void kernel_launch(void* const* d_in, const int* in_sizes, int n_in,
                              void* d_out, int out_size, void* d_ws, size_t ws_size,
                              hipStream_t stream) {
    const int*   sent = (const int*)  d_in[0];
    const float* emb  = (const float*)d_in[1];
    const float* Wihf = (const float*)d_in[2];
    const float* Whhf = (const float*)d_in[3];
    const float* bihf = (const float*)d_in[4];
    const float* bhhf = (const float*)d_in[5];
    const float* Wihb = (const float*)d_in[6];
    const float* Whhb = (const float*)d_in[7];
    const float* bihb = (const float*)d_in[8];
    const float* bhhb = (const float*)d_in[9];
    const float* Wout = (const float*)d_in[10];
    const float* bout = (const float*)d_in[11];
    const float* h0   = (const float*)d_in[12];
    const float* c0   = (const float*)d_in[13];
    float* out = (float*)d_out;

    // workspace layout: pre (128 MB) | hcat (32 MB) | hbuf (16 KB)
    float* pre  = (float*)d_ws;
    float* hcat = pre + (size_t)2 * T_SEQ * G4;
    unsigned long long* hbuf = (unsigned long long*)(hcat + (size_t)T_SEQ * 1024);

    dim3 g1(G4 / 64, T_SEQ / 64, 2);
    k_pre<<<g1, 256, 0, stream>>>(sent, emb, Wihf, Wihb, bihf, bhhf, bihb, bhhb, pre);
    k_scan<<<64, 512, 0, stream>>>(pre, Whhf, Whhb, h0, c0, hcat, hbuf);
    k_out<<<256, 256, 0, stream>>>(hcat, Wout, bout, out);
}